// Round 11
// baseline (532.325 us; speedup 1.0000x reference)
//
#include <hip/hip_runtime.h>
#include <hip/hip_bf16.h>

#define CIN   512
#define COUT  512
#define LEN   8192
#define NB    16
#define KW    3

#define WB_ELEMS (COUT * CIN * KW)

#define PNLB 16512            // 258 rows x 64 B (32 ci bf16)

typedef __attribute__((ext_vector_type(4))) float f32x4;
typedef __attribute__((ext_vector_type(8))) short bf16x8;

static __device__ __forceinline__ unsigned short f2bf(float f) {
    union { float f; unsigned u; } cv; cv.f = f;
    return (unsigned short)((cv.u + 0x7fffu + ((cv.u >> 16) & 1u)) >> 16);
}

// ---- weight dequant-reorder: qweight[co][ci][t] -> wb[co][t*512+ci] (bf16) ----
__global__ __launch_bounds__(256) void wconv_kernel(const int* __restrict__ q,
                                                    unsigned short* __restrict__ wb) {
    int idx = blockIdx.x * 256 + threadIdx.x;
    if (idx >= WB_ELEMS) return;
    int co = idx / (KW * CIN);
    int r  = idx - co * (KW * CIN);
    int t  = r >> 9;
    int ci = r & 511;
    wb[idx] = f2bf((float)q[(co * CIN + ci) * KW + t]);
}

// ---- fused conv: 128x256 tile, chunk=32ci, 3 phases/chunk, A triple-buf, panel dbuf ----
// 2 blocks/CU (57.6 KB LDS, <=128 VGPR via launch_bounds(512,4)).
__global__ __launch_bounds__(512, 4) void conv_kernel(
    const float* __restrict__ x,
    const unsigned short* __restrict__ wb,
    const float* __restrict__ scale_p,
    const float* __restrict__ bias,
    float* __restrict__ out)
{
    __shared__ char sA[3][8192];      // A (weights): 128 co x 32 k bf16, 64B rows, XOR-swz
    __shared__ char sP[2][PNLB];      // x panels: [258 l-rows][32 ci] bf16, XOR-swz

    const int bid = blockIdx.x;
    const int logical = (bid & 7) * 256 + (bid >> 3);   // XCD swizzle, 2048 = 8*256
    const int co_tile = logical & 3;                    // 4 co-tiles share one x panel
    const int l_tile  = logical >> 2;
    const int b   = l_tile >> 5;
    const int l0  = (l_tile & 31) * 256;
    const int co0 = co_tile * 128;

    const int tid  = threadIdx.x;
    const int lane = tid & 63;
    const int wid  = tid >> 6;
    const int wr   = wid >> 2;        // 0..1 (64 co rows)
    const int wc   = wid & 3;         // 0..3 (64 l cols)
    const int lhi  = lane >> 4;
    const int llo  = lane & 15;

    f32x4 acc[4][4] = {};             // co row = m*32 + wr*16 + (lhi*4+j)

    const float* xb = x + (size_t)b * CIN * LEN;
    const char*  wbS = (const char*)wb + (size_t)co0 * 3072;

    // A staging: 1 global_load_lds(16B)/thread/tile; swizzled source, linear dest
    const int aoff = (tid >> 2) * 3072 + (((tid & 3) * 16) ^ (((tid >> 2) & 3) << 4));
    const int adst = tid * 16;
    // A fragment reads: row = m*32 + wr*16 + llo, 64B rows, XOR (row&3)<<4
    const int cA0 = (wr * 16 + llo) * 64 + ((lhi ^ (llo & 3)) << 4);
    // B fragment reads per tap
    const int cB0 = (wc * 64 + llo + 0) * 64 + ((lhi ^ ((llo + 0) & 3)) << 4);
    const int cB1 = (wc * 64 + llo + 1) * 64 + ((lhi ^ ((llo + 1) & 3)) << 4);
    const int cB2 = (wc * 64 + llo + 2) * 64 + ((lhi ^ ((llo + 2) & 3)) << 4);
    // panel write: wave wid owns 4 ci; lane -> l row
    const int colW  = (wid * 8) ^ ((lane & 3) << 4);
    const int lbase = l0 - 1 + lane;

#define BAR()    __builtin_amdgcn_s_barrier()
#define SCHED0() __builtin_amdgcn_sched_barrier(0)
#define LGKM0()  asm volatile("s_waitcnt lgkmcnt(0)" ::: "memory")
#define VMC(N_) do { \
    if ((N_) == 21)      asm volatile("s_waitcnt vmcnt(21)" ::: "memory"); \
    else if ((N_) == 13) asm volatile("s_waitcnt vmcnt(13)" ::: "memory"); \
    else if ((N_) == 9)  asm volatile("s_waitcnt vmcnt(9)"  ::: "memory"); \
    else if ((N_) == 1)  asm volatile("s_waitcnt vmcnt(1)"  ::: "memory"); \
    else if ((N_) == 0)  asm volatile("s_waitcnt vmcnt(0)"  ::: "memory"); } while (0)

#define AGL(BUFI_, KO_) __builtin_amdgcn_global_load_lds(                                    \
    (const __attribute__((address_space(1))) unsigned int*)(wbS + aoff + (KO_)),             \
    (__attribute__((address_space(3))) unsigned int*)(&sA[BUFI_][0] + adst), 16, 0, 0)

#define RA(BUFI_, m_)     (*(const bf16x8*)(&sA[BUFI_][0] + cA0 + (m_) * 2048))
#define RB(PBR_, CB_, n_) (*(const bf16x8*)((PBR_) + (CB_) + (n_) * 1024))

#define BLOAD(S_, V0,V1,V2,V3, XP_) do {                                                     \
    int l_ = lbase + (S_) * 64;                                                              \
    V0 = 0.f; V1 = 0.f; V2 = 0.f; V3 = 0.f;                                                  \
    if ((lane + (S_) * 64 < 258) && ((unsigned)l_ < (unsigned)LEN)) {                        \
        const float* p_ = (XP_) + (size_t)(wid * 4) * LEN + l_;                              \
        V0 = p_[0]; V1 = p_[LEN]; V2 = p_[2 * LEN]; V3 = p_[3 * LEN];                        \
    } } while (0)

#define BPACK(S_, V0,V1,V2,V3, PW_) do {                                                     \
    if (lane + (S_) * 64 < 258) {                                                            \
        uint2 w_;                                                                            \
        w_.x = (unsigned)f2bf(V0) | ((unsigned)f2bf(V1) << 16);                              \
        w_.y = (unsigned)f2bf(V2) | ((unsigned)f2bf(V3) << 16);                              \
        *(uint2*)((PW_) + (lane + (S_) * 64) * 64 + colW) = w_;                              \
    } } while (0)

#define MFMA16() do {                                                                        \
    __builtin_amdgcn_s_setprio(1);                                                           \
    acc[0][0] = __builtin_amdgcn_mfma_f32_16x16x32_bf16(a0, b0, acc[0][0], 0, 0, 0);         \
    acc[0][1] = __builtin_amdgcn_mfma_f32_16x16x32_bf16(a0, b1, acc[0][1], 0, 0, 0);         \
    acc[0][2] = __builtin_amdgcn_mfma_f32_16x16x32_bf16(a0, b2, acc[0][2], 0, 0, 0);         \
    acc[0][3] = __builtin_amdgcn_mfma_f32_16x16x32_bf16(a0, b3, acc[0][3], 0, 0, 0);         \
    acc[1][0] = __builtin_amdgcn_mfma_f32_16x16x32_bf16(a1, b0, acc[1][0], 0, 0, 0);         \
    acc[1][1] = __builtin_amdgcn_mfma_f32_16x16x32_bf16(a1, b1, acc[1][1], 0, 0, 0);         \
    acc[1][2] = __builtin_amdgcn_mfma_f32_16x16x32_bf16(a1, b2, acc[1][2], 0, 0, 0);         \
    acc[1][3] = __builtin_amdgcn_mfma_f32_16x16x32_bf16(a1, b3, acc[1][3], 0, 0, 0);         \
    acc[2][0] = __builtin_amdgcn_mfma_f32_16x16x32_bf16(a2, b0, acc[2][0], 0, 0, 0);         \
    acc[2][1] = __builtin_amdgcn_mfma_f32_16x16x32_bf16(a2, b1, acc[2][1], 0, 0, 0);         \
    acc[2][2] = __builtin_amdgcn_mfma_f32_16x16x32_bf16(a2, b2, acc[2][2], 0, 0, 0);         \
    acc[2][3] = __builtin_amdgcn_mfma_f32_16x16x32_bf16(a2, b3, acc[2][3], 0, 0, 0);         \
    acc[3][0] = __builtin_amdgcn_mfma_f32_16x16x32_bf16(a3, b0, acc[3][0], 0, 0, 0);         \
    acc[3][1] = __builtin_amdgcn_mfma_f32_16x16x32_bf16(a3, b1, acc[3][1], 0, 0, 0);         \
    acc[3][2] = __builtin_amdgcn_mfma_f32_16x16x32_bf16(a3, b2, acc[3][2], 0, 0, 0);         \
    acc[3][3] = __builtin_amdgcn_mfma_f32_16x16x32_bf16(a3, b3, acc[3][3], 0, 0, 0);         \
    __builtin_amdgcn_s_setprio(0);                                                           \
    } while (0)

    bf16x8 a0, a1, a2, a3, b0, b1, b2, b3;
    float e0, e1, e2, e3, o0, o1, o2, o3, f0, f1, f2, f3;

    char* const pbA = &sP[0][0];
    char* const pbB = &sP[1][0];

    // ---------- prologue: panel 0 + A tiles 0,1 ----------
    BLOAD(0, e0,e1,e2,e3, xb); BLOAD(1, o0,o1,o2,o3, xb); BLOAD(2, f0,f1,f2,f3, xb);
    BPACK(0, e0,e1,e2,e3, pbA); BPACK(1, o0,o1,o2,o3, pbA); BPACK(2, f0,f1,f2,f3, pbA);
    BLOAD(3, e0,e1,e2,e3, xb); BLOAD(4, o0,o1,o2,o3, xb);
    BPACK(3, e0,e1,e2,e3, pbA); BPACK(4, o0,o1,o2,o3, pbA);
    AGL(0, 0); AGL(1, 1024);
    VMC(0); LGKM0(); BAR(); SCHED0();

    // Per chunk q (3 phases t0/t1/t2): read A buf t (tile 3q+t), stage tile 3q+t+2
    // into buf (t+2)%3; load panel q+1 during t0/t1, pack t1/t2, publish at t2.
    // vmcnt {13,21,9} waits exactly the 1-phase-old AGL (BLOADs stay in flight).
#define CHUNK(PBR_, PBW_, STG_, LAST_) do {                                                  \
    /* t0 */                                                                                 \
    SCHED0();                                                                                \
    AGL(2, kq + 2048);                                                                       \
    if (STG_) { BLOAD(0, e0,e1,e2,e3, xnext); BLOAD(1, o0,o1,o2,o3, xnext);                  \
                BLOAD(2, f0,f1,f2,f3, xnext); }                                              \
    a0 = RA(0,0); a1 = RA(0,1); a2 = RA(0,2); a3 = RA(0,3);                                  \
    b0 = RB(PBR_, cB0, 0); b1 = RB(PBR_, cB0, 1);                                            \
    b2 = RB(PBR_, cB0, 2); b3 = RB(PBR_, cB0, 3);                                            \
    VMC((STG_) ? 13 : 1);                                                                    \
    BAR(); LGKM0(); SCHED0();                                                                \
    MFMA16();                                                                                \
    /* t1 */                                                                                 \
    SCHED0();                                                                                \
    if (STG_) { BPACK(0, e0,e1,e2,e3, PBW_); BPACK(1, o0,o1,o2,o3, PBW_);                    \
                BPACK(2, f0,f1,f2,f3, PBW_); }                                               \
    if (!(LAST_)) AGL(0, kq + 64);                                                           \
    if (STG_) { BLOAD(3, e0,e1,e2,e3, xnext); BLOAD(4, o0,o1,o2,o3, xnext); }                \
    a0 = RA(1,0); a1 = RA(1,1); a2 = RA(1,2); a3 = RA(1,3);                                  \
    b0 = RB(PBR_, cB1, 0); b1 = RB(PBR_, cB1, 1);                                            \
    b2 = RB(PBR_, cB1, 2); b3 = RB(PBR_, cB1, 3);                                            \
    VMC((STG_) ? 21 : 0);                                                                    \
    BAR(); LGKM0(); SCHED0();                                                                \
    MFMA16();                                                                                \
    /* t2 */                                                                                 \
    SCHED0();                                                                                \
    if (STG_) { BPACK(3, e0,e1,e2,e3, PBW_); BPACK(4, o0,o1,o2,o3, PBW_); }                  \
    if (!(LAST_)) AGL(1, kq + 1088);                                                         \
    a0 = RA(2,0); a1 = RA(2,1); a2 = RA(2,2); a3 = RA(2,3);                                  \
    b0 = RB(PBR_, cB2, 0); b1 = RB(PBR_, cB2, 1);                                            \
    b2 = RB(PBR_, cB2, 2); b3 = RB(PBR_, cB2, 3);                                            \
    LGKM0();                     /* publish panel ds_writes (and drain own reads) */         \
    if (!(LAST_)) { VMC(9); BAR(); }                                                         \
    SCHED0();                                                                                \
    MFMA16();                                                                                \
    kq += 64; xnext += 32 * LEN;                                                             \
    } while (0)

    int kq = 0;
    const float* xnext = xb + 32 * LEN;   // chunk q stages panel q+1

    #pragma unroll 1
    for (int qq = 0; qq < 7; ++qq) {      // q = 0..13
        CHUNK(pbA, pbB, 1, 0);
        CHUNK(pbB, pbA, 1, 0);
    }
    CHUNK(pbA, pbB, 1, 0);                // q = 14 (stages panel 15)
    CHUNK(pbB, pbA, 0, 1);                // q = 15 (tail)

#undef CHUNK
#undef AGL
#undef RA
#undef RB
#undef BLOAD
#undef BPACK
#undef MFMA16

    const float sc = scale_p[0];
    #pragma unroll
    for (int m = 0; m < 4; ++m) {
        #pragma unroll
        for (int j = 0; j < 4; ++j) {
            int co = co0 + m * 32 + wr * 16 + lhi * 4 + j;
            float bv = bias[co];
            size_t orow = ((size_t)b * COUT + co) * LEN + l0 + wc * 64;
            #pragma unroll
            for (int n = 0; n < 4; ++n)
                out[orow + n * 16 + llo] = sc * acc[m][n][j] + bv;
        }
    }
}

extern "C" void kernel_launch(void* const* d_in, const int* in_sizes, int n_in,
                              void* d_out, int out_size, void* d_ws, size_t ws_size,
                              hipStream_t stream) {
    const float* x    = (const float*)d_in[0];
    const int*   qw   = (const int*)d_in[1];
    const float* sc   = (const float*)d_in[2];
    const float* bias = (const float*)d_in[3];
    float* out = (float*)d_out;
    unsigned short* wb = (unsigned short*)d_ws;   // 1.5 MB

    wconv_kernel<<<(WB_ELEMS + 255) / 256, 256, 0, stream>>>(qw, wb);
    conv_kernel<<<2048, 512, 0, stream>>>(x, wb, sc, bias, out);
}

// Round 12
// 323.790 us; speedup vs baseline: 1.6440x; 1.6440x over previous
//
#include <hip/hip_runtime.h>
#include <hip/hip_bf16.h>

#define CIN   512
#define COUT  512
#define LEN   8192
#define NB    16
#define KW    3
#define PROWS 8200          // padded l-rows per batch (p = l+1)

#define WB_ELEMS (COUT * CIN * KW)
#define WB_BYTES ((size_t)WB_ELEMS * 2)
#define XS_BYTES ((size_t)NB * PROWS * CIN * 2)

typedef __attribute__((ext_vector_type(4))) float f32x4;
typedef __attribute__((ext_vector_type(8))) short bf16x8;

static __device__ __forceinline__ unsigned short f2bf(float f) {
    union { float f; unsigned u; } cv; cv.f = f;
    return (unsigned short)((cv.u + 0x7fffu + ((cv.u >> 16) & 1u)) >> 16);
}

// ---- weight dequant-reorder: qweight[co][ci][t] -> wb[co][t*512+ci] (bf16) ----
__global__ __launch_bounds__(256) void wconv_kernel(const int* __restrict__ q,
                                                    unsigned short* __restrict__ wb) {
    int idx = blockIdx.x * 256 + threadIdx.x;
    if (idx >= WB_ELEMS) return;
    int co = idx / (KW * CIN);
    int r  = idx - co * (KW * CIN);
    int t  = r >> 9;
    int ci = r & 511;
    wb[idx] = f2bf((float)q[(co * CIN + ci) * KW + t]);
}

// ---- x prepass: fp32 [b][ci][l] -> bf16 [b][1+l][ci]; zero halo rows ----
__global__ __launch_bounds__(256) void xprep_kernel(const float* __restrict__ x,
                                                    unsigned short* __restrict__ xs) {
    __shared__ char T[64 * 132];
    int blk = blockIdx.x;
    int b   = blk >> 10;
    int ci0 = ((blk >> 7) & 7) * 64;
    int l0  = (blk & 127) * 64;
    int tid = threadIdx.x;

    if (l0 == 0 && tid < 64)
        xs[((size_t)b * PROWS + 0) * CIN + ci0 + tid] = 0;
    if (l0 == (LEN - 64) && tid < 64)
        xs[((size_t)b * PROWS + (LEN + 1)) * CIN + ci0 + tid] = 0;

    const float* src = x + ((size_t)b * CIN + ci0) * LEN + l0;
    for (int i = tid; i < 64 * 16; i += 256) {
        int r = i >> 4, c4 = i & 15;
        f32x4 v = *(const f32x4*)(src + (size_t)r * LEN + c4 * 4);
        unsigned lo = (unsigned)f2bf(v[0]) | ((unsigned)f2bf(v[1]) << 16);
        unsigned hi = (unsigned)f2bf(v[2]) | ((unsigned)f2bf(v[3]) << 16);
        char* p = T + r * 132 + c4 * 8;
        *(unsigned*)p       = lo;
        *(unsigned*)(p + 4) = hi;
    }
    __syncthreads();
    unsigned short* dst = xs + ((size_t)b * PROWS + 1 + l0) * CIN + ci0;
    for (int i = tid; i < 64 * 8; i += 256) {
        int l = i >> 3, c8 = i & 7;
        union { bf16x8 v; unsigned short s[8]; } pk;
        #pragma unroll
        for (int j = 0; j < 8; ++j)
            pk.s[j] = *(const unsigned short*)(T + (c8 * 8 + j) * 132 + l * 2);
        *(bf16x8*)(dst + (size_t)l * CIN + c8 * 8) = pk.v;
    }
}

// ---- main conv: 128x128 tile, 4 waves, 2 blocks/CU (cross-block TLP), BK=64 ----
__global__ __launch_bounds__(256, 2) void conv_kernel(
    const unsigned short* __restrict__ xs,
    const unsigned short* __restrict__ wb,
    const float* __restrict__ scale_p,
    const float* __restrict__ bias,
    float* __restrict__ out)
{
    __shared__ char sA[2][16384];    // A: 128 co x 64 k bf16, 128B rows, XOR-swz
    __shared__ char sB[2][16384];    // B: 128 l  x 64 k bf16

    const int bid = blockIdx.x;
    const int logical = (bid & 7) * 512 + (bid >> 3);   // XCD swizzle, 4096 = 8*512
    const int co_tile = logical & 3;                    // 4 co-tiles share one x panel
    const int n_tile  = logical >> 2;
    const int b   = n_tile >> 6;
    const int l0  = (n_tile & 63) * 128;
    const int co0 = co_tile * 128;

    const int tid  = threadIdx.x;
    const int lane = tid & 63;
    const int wid  = tid >> 6;        // 0..3
    const int wr   = wid >> 1;        // 0..1 (64 co rows)
    const int wc   = wid & 1;         // 0..1 (64 l cols)
    const int lhi  = lane >> 4;
    const int llo  = lane & 15;

    f32x4 acc[4][4] = {};             // wave tile 64x64

    const char* xsB = (const char*)(xs + ((size_t)b * PROWS + l0) * CIN);
    const char* wbB = (const char*)wb + (size_t)co0 * 3072;

    // staging: 4 gloads/thread per operand; it = tid + k*256, r = it>>3, q = it&7
    const int r0 = (tid + 0)   >> 3, q0 = tid & 7;
    const int r1 = (tid + 256) >> 3;
    const int r2 = (tid + 512) >> 3;
    const int r3 = (tid + 768) >> 3;
    const int s0 = (q0 * 16) ^ ((r0 & 7) << 4);
    const int s1 = (q0 * 16) ^ ((r1 & 7) << 4);
    const int s2_ = (q0 * 16) ^ ((r2 & 7) << 4);
    const int s3 = (q0 * 16) ^ ((r3 & 7) << 4);
    const int vA0 = r0 * 3072 + s0, vA1 = r1 * 3072 + s1, vA2 = r2 * 3072 + s2_, vA3 = r3 * 3072 + s3;
    const int vB0 = r0 * 1024 + s0, vB1 = r1 * 1024 + s1, vB2 = r2 * 1024 + s2_, vB3 = r3 * 1024 + s3;
    const int d0 = tid * 16;

    // fragment read bases (128B rows, XOR (row&7)<<4; row&7 == llo&7)
    const int t10 = llo & 3, t2 = (llo >> 2) & 1;
    const int cAa = (wr * 64 + llo) * 128 + ((lhi ^ t10) << 4);
    const int cBa = (wc * 64 + llo) * 128 + ((lhi ^ t10) << 4);
    const char* pA0 = &sA[0][0] + cAa + (t2 ? 64 : 0);   // k=0
    const char* pA1 = &sA[0][0] + cAa + (t2 ? 0 : 64);   // k=1
    const char* pB0 = &sB[0][0] + cBa + (t2 ? 64 : 0);
    const char* pB1 = &sB[0][0] + cBa + (t2 ? 0 : 64);

#define BAR()    __builtin_amdgcn_s_barrier()
#define SCHED0() __builtin_amdgcn_sched_barrier(0)
#define LGKM0()  asm volatile("s_waitcnt lgkmcnt(0)" ::: "memory")

#define GL(src_, dst_) __builtin_amdgcn_global_load_lds(                                     \
    (const __attribute__((address_space(1))) unsigned int*)(src_),                           \
    (__attribute__((address_space(3))) unsigned int*)(dst_), 16, 0, 0)

#define STAGE(NB_, KO_) do {                                                                 \
    GL(wbB + vA0 + (KO_), &sA[NB_][0] + d0);                                                 \
    GL(wbB + vA1 + (KO_), &sA[NB_][0] + d0 + 4096);                                          \
    GL(wbB + vA2 + (KO_), &sA[NB_][0] + d0 + 8192);                                          \
    GL(wbB + vA3 + (KO_), &sA[NB_][0] + d0 + 12288);                                         \
    GL(xsB + vB0 + (KO_), &sB[NB_][0] + d0);                                                 \
    GL(xsB + vB1 + (KO_), &sB[NB_][0] + d0 + 4096);                                          \
    GL(xsB + vB2 + (KO_), &sB[NB_][0] + d0 + 8192);                                          \
    GL(xsB + vB3 + (KO_), &sB[NB_][0] + d0 + 12288);                                         \
    } while (0)

#define RF(P_, BUF_, m_) (*(const bf16x8*)((P_) + (BUF_) * 16384 + (m_) * 2048))

#define MFMA16() do {                                                                        \
    __builtin_amdgcn_s_setprio(1);                                                           \
    acc[0][0] = __builtin_amdgcn_mfma_f32_16x16x32_bf16(a0, b0, acc[0][0], 0, 0, 0);         \
    acc[0][1] = __builtin_amdgcn_mfma_f32_16x16x32_bf16(a0, b1, acc[0][1], 0, 0, 0);         \
    acc[0][2] = __builtin_amdgcn_mfma_f32_16x16x32_bf16(a0, b2, acc[0][2], 0, 0, 0);         \
    acc[0][3] = __builtin_amdgcn_mfma_f32_16x16x32_bf16(a0, b3, acc[0][3], 0, 0, 0);         \
    acc[1][0] = __builtin_amdgcn_mfma_f32_16x16x32_bf16(a1, b0, acc[1][0], 0, 0, 0);         \
    acc[1][1] = __builtin_amdgcn_mfma_f32_16x16x32_bf16(a1, b1, acc[1][1], 0, 0, 0);         \
    acc[1][2] = __builtin_amdgcn_mfma_f32_16x16x32_bf16(a1, b2, acc[1][2], 0, 0, 0);         \
    acc[1][3] = __builtin_amdgcn_mfma_f32_16x16x32_bf16(a1, b3, acc[1][3], 0, 0, 0);         \
    acc[2][0] = __builtin_amdgcn_mfma_f32_16x16x32_bf16(a2, b0, acc[2][0], 0, 0, 0);         \
    acc[2][1] = __builtin_amdgcn_mfma_f32_16x16x32_bf16(a2, b1, acc[2][1], 0, 0, 0);         \
    acc[2][2] = __builtin_amdgcn_mfma_f32_16x16x32_bf16(a2, b2, acc[2][2], 0, 0, 0);         \
    acc[2][3] = __builtin_amdgcn_mfma_f32_16x16x32_bf16(a2, b3, acc[2][3], 0, 0, 0);         \
    acc[3][0] = __builtin_amdgcn_mfma_f32_16x16x32_bf16(a3, b0, acc[3][0], 0, 0, 0);         \
    acc[3][1] = __builtin_amdgcn_mfma_f32_16x16x32_bf16(a3, b1, acc[3][1], 0, 0, 0);         \
    acc[3][2] = __builtin_amdgcn_mfma_f32_16x16x32_bf16(a3, b2, acc[3][2], 0, 0, 0);         \
    acc[3][3] = __builtin_amdgcn_mfma_f32_16x16x32_bf16(a3, b3, acc[3][3], 0, 0, 0);         \
    __builtin_amdgcn_s_setprio(0);                                                           \
    } while (0)

// tile c (2 phases): p0 stages ALL of tile c+1 then computes k0; p1 computes k1
// and drains the (1-phase-old) stage with vmcnt(0) before its barrier.
#define TILE(BUF, NBUF) do {                                                                 \
    SCHED0();                                                                                \
    STAGE(NBUF, koff);                                                                       \
    a0 = RF(pA0, BUF, 0); a1 = RF(pA0, BUF, 1); a2 = RF(pA0, BUF, 2); a3 = RF(pA0, BUF, 3);  \
    b0 = RF(pB0, BUF, 0); b1 = RF(pB0, BUF, 1); b2 = RF(pB0, BUF, 2); b3 = RF(pB0, BUF, 3);  \
    BAR(); LGKM0(); SCHED0();                                                                \
    MFMA16();                                                                                \
    SCHED0();                                                                                \
    a0 = RF(pA1, BUF, 0); a1 = RF(pA1, BUF, 1); a2 = RF(pA1, BUF, 2); a3 = RF(pA1, BUF, 3);  \
    b0 = RF(pB1, BUF, 0); b1 = RF(pB1, BUF, 1); b2 = RF(pB1, BUF, 2); b3 = RF(pB1, BUF, 3);  \
    asm volatile("s_waitcnt vmcnt(0)" ::: "memory");                                         \
    BAR(); LGKM0(); SCHED0();                                                                \
    MFMA16();                                                                                \
    koff += (tapn == 2) ? -1920 : 1024;                                                      \
    tapn  = (tapn == 2) ? 0 : tapn + 1;                                                      \
    } while (0)

    bf16x8 a0, a1, a2, a3, b0, b1, b2, b3;

    // prologue: stage tile 0 (tap0, ci0=0) into buf0
    STAGE(0, 0);
    int koff = 1024, tapn = 1;        // tile 1
    asm volatile("s_waitcnt vmcnt(0)" ::: "memory");
    BAR(); SCHED0();

    #pragma unroll 1
    for (int cc = 0; cc < 11; ++cc) { // tiles 0..21
        TILE(0, 1);
        TILE(1, 0);
    }
    TILE(0, 1);                       // tile 22 (stages tile 23 into buf1)
    // tail: tile 23 (buf1), no stages, no barriers needed
    {
        SCHED0();
        a0 = RF(pA0, 1, 0); a1 = RF(pA0, 1, 1); a2 = RF(pA0, 1, 2); a3 = RF(pA0, 1, 3);
        b0 = RF(pB0, 1, 0); b1 = RF(pB0, 1, 1); b2 = RF(pB0, 1, 2); b3 = RF(pB0, 1, 3);
        LGKM0(); SCHED0();
        MFMA16();
        SCHED0();
        a0 = RF(pA1, 1, 0); a1 = RF(pA1, 1, 1); a2 = RF(pA1, 1, 2); a3 = RF(pA1, 1, 3);
        b0 = RF(pB1, 1, 0); b1 = RF(pB1, 1, 1); b2 = RF(pB1, 1, 2); b3 = RF(pB1, 1, 3);
        LGKM0(); SCHED0();
        MFMA16();
    }
#undef TILE
#undef STAGE
#undef GL
#undef RF
#undef MFMA16

    const float sc = scale_p[0];
    #pragma unroll
    for (int m = 0; m < 4; ++m) {
        #pragma unroll
        for (int j = 0; j < 4; ++j) {
            int co = co0 + wr * 64 + m * 16 + lhi * 4 + j;
            float bv = bias[co];
            size_t orow = ((size_t)b * COUT + co) * LEN + l0 + wc * 64;
            #pragma unroll
            for (int n = 0; n < 4; ++n)
                out[orow + n * 16 + llo] = sc * acc[m][n][j] + bv;
        }
    }
}

// ---- fallback (no x prepass) — only if ws too small ----
__global__ __launch_bounds__(256, 2) void conv_fb_kernel(
    const float* __restrict__ x,
    const unsigned short* __restrict__ wb,
    const float* __restrict__ scale_p,
    const float* __restrict__ bias,
    float* __restrict__ out)
{
    __shared__ char xT[132 * 128];
    const int bid = blockIdx.x;
    const int logical = (bid & 7) * 512 + (bid >> 3);
    const int co_tile = logical & 3;
    const int n_tile  = logical >> 2;
    const int b   = n_tile >> 6;
    const int l0  = (n_tile & 63) * 128;
    const int co0 = co_tile * 128;
    const int tid  = threadIdx.x;
    const int lane = tid & 63;
    const int wid  = tid >> 6;
    const int wr = wid >> 1, wc = wid & 1;
    const int lhi = lane >> 4;
    const int llo = lane & 15;
    f32x4 acc[4][4] = {};
    const float* xb = x + (size_t)b * CIN * LEN;

    for (int ci0 = 0; ci0 < CIN; ci0 += 64) {
        __syncthreads();
        for (int it = tid; it < 132 * 8; it += 256) {
            int c = it % 132;
            int o = it / 132;
            int l = l0 - 1 + c;
            float v[8];
            if (l >= 0 && l < LEN) {
                const float* src = xb + (size_t)(ci0 + o * 8) * LEN + l;
                #pragma unroll
                for (int j = 0; j < 8; ++j) v[j] = src[(size_t)j * LEN];
            } else {
                #pragma unroll
                for (int j = 0; j < 8; ++j) v[j] = 0.f;
            }
            union { bf16x8 v8; unsigned short s[8]; } pk;
            #pragma unroll
            for (int j = 0; j < 8; ++j) pk.s[j] = f2bf(v[j]);
            int byte = c * 128 + ((o * 16) ^ ((c & 7) << 4));
            *reinterpret_cast<bf16x8*>(xT + byte) = pk.v8;
        }
        __syncthreads();
        #pragma unroll
        for (int t = 0; t < KW; ++t) {
            #pragma unroll
            for (int s = 0; s < 2; ++s) {
                bf16x8 af[4];
                #pragma unroll
                for (int m = 0; m < 4; ++m)
                    af[m] = *reinterpret_cast<const bf16x8*>(
                        wb + (size_t)(co0 + wr * 64 + m * 16 + llo) * (KW * CIN)
                           + t * CIN + ci0 + s * 32 + 8 * lhi);
                bf16x8 bfr[4];
                #pragma unroll
                for (int n = 0; n < 4; ++n) {
                    int col = wc * 64 + n * 16 + llo + t;
                    int byte = col * 128 + (((s * 32 + 8 * lhi) * 2) ^ ((col & 7) << 4));
                    bfr[n] = *reinterpret_cast<const bf16x8*>(xT + byte);
                }
                #pragma unroll
                for (int m = 0; m < 4; ++m)
                    #pragma unroll
                    for (int n = 0; n < 4; ++n)
                        acc[m][n] = __builtin_amdgcn_mfma_f32_16x16x32_bf16(af[m], bfr[n], acc[m][n], 0, 0, 0);
            }
        }
    }
    const float sc = scale_p[0];
    #pragma unroll
    for (int m = 0; m < 4; ++m) {
        #pragma unroll
        for (int j = 0; j < 4; ++j) {
            int co = co0 + wr * 64 + m * 16 + lhi * 4 + j;
            float bv = bias[co];
            size_t orow = ((size_t)b * COUT + co) * LEN + l0 + wc * 64;
            #pragma unroll
            for (int n = 0; n < 4; ++n)
                out[orow + n * 16 + llo] = sc * acc[m][n][j] + bv;
        }
    }
}

extern "C" void kernel_launch(void* const* d_in, const int* in_sizes, int n_in,
                              void* d_out, int out_size, void* d_ws, size_t ws_size,
                              hipStream_t stream) {
    const float* x    = (const float*)d_in[0];
    const int*   qw   = (const int*)d_in[1];
    const float* sc   = (const float*)d_in[2];
    const float* bias = (const float*)d_in[3];
    float* out = (float*)d_out;
    unsigned short* wb = (unsigned short*)d_ws;

    wconv_kernel<<<(WB_ELEMS + 255) / 256, 256, 0, stream>>>(qw, wb);

    if (ws_size >= WB_BYTES + XS_BYTES) {
        unsigned short* xsw = (unsigned short*)((char*)d_ws + WB_BYTES);
        xprep_kernel<<<NB * 8 * (LEN / 64), 256, 0, stream>>>(x, xsw);
        conv_kernel<<<4096, 256, 0, stream>>>(xsw, wb, sc, bias, out);
    } else {
        conv_fb_kernel<<<4096, 256, 0, stream>>>(x, wb, sc, bias, out);
    }
}

// Round 13
// 305.994 us; speedup vs baseline: 1.7397x; 1.0582x over previous
//
#include <hip/hip_runtime.h>
#include <hip/hip_bf16.h>

#define CIN   512
#define COUT  512
#define LEN   8192
#define NB    16
#define KW    3
#define PROWS 8200          // padded l-rows per batch (p = l+1)

#define WB_ELEMS (COUT * CIN * KW)
#define WB_BYTES ((size_t)WB_ELEMS * 2)
#define XS_BYTES ((size_t)NB * PROWS * CIN * 2)

// main kernel: 256x256 tile, BK=64, 8 waves, 8-phase with TWO barriers/tile
// (p1/p3 barriers removed after WAR audit: region-disjoint or 2-barrier-separated)
#define BM2 256
#define BN2 256
#define BK3 64
#define NT  24               // K-tiles, tap innermost
#define TILE3 (BM2 * BK3 * 2)

typedef __attribute__((ext_vector_type(4))) float f32x4;
typedef __attribute__((ext_vector_type(8))) short bf16x8;

static __device__ __forceinline__ unsigned short f2bf(float f) {
    union { float f; unsigned u; } cv; cv.f = f;
    return (unsigned short)((cv.u + 0x7fffu + ((cv.u >> 16) & 1u)) >> 16);
}

// ---- weight dequant-reorder: qweight[co][ci][t] -> wb[co][t*512+ci] (bf16) ----
__global__ __launch_bounds__(256) void wconv_kernel(const int* __restrict__ q,
                                                    unsigned short* __restrict__ wb) {
    int idx = blockIdx.x * 256 + threadIdx.x;
    if (idx >= WB_ELEMS) return;
    int co = idx / (KW * CIN);
    int r  = idx - co * (KW * CIN);
    int t  = r >> 9;
    int ci = r & 511;
    wb[idx] = f2bf((float)q[(co * CIN + ci) * KW + t]);
}

// ---- x prepass: fp32 [b][ci][l] -> bf16 [b][1+l][ci]; zero halo rows ----
__global__ __launch_bounds__(256) void xprep_kernel(const float* __restrict__ x,
                                                    unsigned short* __restrict__ xs) {
    __shared__ char T[64 * 132];
    int blk = blockIdx.x;
    int b   = blk >> 10;
    int ci0 = ((blk >> 7) & 7) * 64;
    int l0  = (blk & 127) * 64;
    int tid = threadIdx.x;

    if (l0 == 0 && tid < 64)
        xs[((size_t)b * PROWS + 0) * CIN + ci0 + tid] = 0;
    if (l0 == (LEN - 64) && tid < 64)
        xs[((size_t)b * PROWS + (LEN + 1)) * CIN + ci0 + tid] = 0;

    const float* src = x + ((size_t)b * CIN + ci0) * LEN + l0;
    for (int i = tid; i < 64 * 16; i += 256) {
        int r = i >> 4, c4 = i & 15;
        f32x4 v = *(const f32x4*)(src + (size_t)r * LEN + c4 * 4);
        unsigned lo = (unsigned)f2bf(v[0]) | ((unsigned)f2bf(v[1]) << 16);
        unsigned hi = (unsigned)f2bf(v[2]) | ((unsigned)f2bf(v[3]) << 16);
        char* p = T + r * 132 + c4 * 8;
        *(unsigned*)p       = lo;
        *(unsigned*)(p + 4) = hi;
    }
    __syncthreads();
    unsigned short* dst = xs + ((size_t)b * PROWS + 1 + l0) * CIN + ci0;
    for (int i = tid; i < 64 * 8; i += 256) {
        int l = i >> 3, c8 = i & 7;
        union { bf16x8 v; unsigned short s[8]; } pk;
        #pragma unroll
        for (int j = 0; j < 8; ++j)
            pk.s[j] = *(const unsigned short*)(T + (c8 * 8 + j) * 132 + l * 2);
        *(bf16x8*)(dst + (size_t)l * CIN + c8 * 8) = pk.v;
    }
}

// ---- main conv: 2 barriers per K-tile, counted vmcnt, region-disjoint WAR ----
__global__ __launch_bounds__(512, 2) void conv_kernel(
    const unsigned short* __restrict__ xs,
    const unsigned short* __restrict__ wb,
    const float* __restrict__ scale_p,
    const float* __restrict__ bias,
    float* __restrict__ out)
{
    __shared__ char sA[2][TILE3];    // 2 x 32 KB
    __shared__ char sB[2][TILE3];    // 2 x 32 KB

    const int bid = blockIdx.x;
    const int logical = (bid & 7) * 128 + (bid >> 3);   // XCD swizzle, 1024 = 8*128
    const int co_tile = logical & 1;
    const int l_tile  = logical >> 1;
    const int b   = l_tile >> 5;
    const int l0  = (l_tile & 31) * BN2;
    const int co0 = co_tile * BM2;

    const int tid  = threadIdx.x;
    const int lane = tid & 63;
    const int wid  = tid >> 6;
    const int wr   = wid >> 2;        // 0..1
    const int wc   = wid & 3;         // 0..3
    const int lhi  = lane >> 4;
    const int llo  = lane & 15;

    f32x4 acc[8][4] = {};             // row = m*32 + wr*16 (interleaved map)

    const char* xsB = (const char*)(xs + ((size_t)b * PROWS + l0) * CIN);
    const char* wbB = (const char*)wb + (size_t)co0 * (KW * CIN * 2);

    // stage unit u of K-tile c into buf: u0=B rows0-127, u1=B rows128-255, u2=A h0, u3=A h1
#define STAGEU(buf_, c_, u_) do {                                                            \
    int tap_ = (c_) % KW;  int ci0_ = ((c_) / KW) * BK3;                                     \
    int rowoff_ = ((u_) & 1) * 128;                                                          \
    const char* src0_; size_t rstride_; char* dst0_;                                         \
    if ((u_) < 2) { src0_ = xsB + ((size_t)(tap_ + rowoff_) * CIN + ci0_) * 2;               \
                    rstride_ = CIN * 2; dst0_ = &sB[buf_][rowoff_ * 128]; }                   \
    else          { src0_ = wbB + (size_t)rowoff_ * (KW * CIN * 2)                           \
                            + ((size_t)tap_ * CIN + ci0_) * 2;                               \
                    rstride_ = KW * CIN * 2; dst0_ = &sA[buf_][rowoff_ * 128]; }             \
    _Pragma("unroll")                                                                        \
    for (int kk_ = 0; kk_ < 2; ++kk_) {                                                      \
        int it_ = tid + kk_ * 512;                                                           \
        int r_ = it_ >> 3, q_ = it_ & 7;                                                     \
        __builtin_amdgcn_global_load_lds(                                                    \
            (const __attribute__((address_space(1))) unsigned int*)                          \
                (src0_ + (size_t)r_ * rstride_ + ((q_ * 16) ^ ((r_ & 7) << 4))),             \
            (__attribute__((address_space(3))) unsigned int*)(dst0_ + it_ * 16),             \
            16, 0, 0);                                                                       \
    } } while (0)

#define LDA(d_, buf_, mq_, k_) do { int row_ = (mq_) * 32 + wr * 16 + llo;                   \
    d_ = *(const bf16x8*)(&sA[buf_][0] + row_ * 128                                          \
                          + (((k_) * 64 + lhi * 16) ^ ((row_ & 7) << 4))); } while (0)
#define LDB(d_, buf_, n_, k_) do { int row_ = wc * 64 + (n_) * 16 + llo;                     \
    d_ = *(const bf16x8*)(&sB[buf_][0] + row_ * 128                                          \
                          + (((k_) * 64 + lhi * 16) ^ ((row_ & 7) << 4))); } while (0)

#define MFMA16(p_) do {                                                                      \
    __builtin_amdgcn_s_setprio(1);                                                           \
    acc[2*(p_)  ][0] = __builtin_amdgcn_mfma_f32_16x16x32_bf16(a0_, bB00, acc[2*(p_)  ][0],0,0,0); \
    acc[2*(p_)  ][1] = __builtin_amdgcn_mfma_f32_16x16x32_bf16(a0_, bB10, acc[2*(p_)  ][1],0,0,0); \
    acc[2*(p_)  ][2] = __builtin_amdgcn_mfma_f32_16x16x32_bf16(a0_, bB20, acc[2*(p_)  ][2],0,0,0); \
    acc[2*(p_)  ][3] = __builtin_amdgcn_mfma_f32_16x16x32_bf16(a0_, bB30, acc[2*(p_)  ][3],0,0,0); \
    acc[2*(p_)+1][0] = __builtin_amdgcn_mfma_f32_16x16x32_bf16(a2_, bB00, acc[2*(p_)+1][0],0,0,0); \
    acc[2*(p_)+1][1] = __builtin_amdgcn_mfma_f32_16x16x32_bf16(a2_, bB10, acc[2*(p_)+1][1],0,0,0); \
    acc[2*(p_)+1][2] = __builtin_amdgcn_mfma_f32_16x16x32_bf16(a2_, bB20, acc[2*(p_)+1][2],0,0,0); \
    acc[2*(p_)+1][3] = __builtin_amdgcn_mfma_f32_16x16x32_bf16(a2_, bB30, acc[2*(p_)+1][3],0,0,0); \
    acc[2*(p_)  ][0] = __builtin_amdgcn_mfma_f32_16x16x32_bf16(a1_, bB01, acc[2*(p_)  ][0],0,0,0); \
    acc[2*(p_)  ][1] = __builtin_amdgcn_mfma_f32_16x16x32_bf16(a1_, bB11, acc[2*(p_)  ][1],0,0,0); \
    acc[2*(p_)  ][2] = __builtin_amdgcn_mfma_f32_16x16x32_bf16(a1_, bB21, acc[2*(p_)  ][2],0,0,0); \
    acc[2*(p_)  ][3] = __builtin_amdgcn_mfma_f32_16x16x32_bf16(a1_, bB31, acc[2*(p_)  ][3],0,0,0); \
    acc[2*(p_)+1][0] = __builtin_amdgcn_mfma_f32_16x16x32_bf16(a3_, bB01, acc[2*(p_)+1][0],0,0,0); \
    acc[2*(p_)+1][1] = __builtin_amdgcn_mfma_f32_16x16x32_bf16(a3_, bB11, acc[2*(p_)+1][1],0,0,0); \
    acc[2*(p_)+1][2] = __builtin_amdgcn_mfma_f32_16x16x32_bf16(a3_, bB21, acc[2*(p_)+1][2],0,0,0); \
    acc[2*(p_)+1][3] = __builtin_amdgcn_mfma_f32_16x16x32_bf16(a3_, bB31, acc[2*(p_)+1][3],0,0,0); \
    __builtin_amdgcn_s_setprio(0);                                                           \
    } while (0)

#define BAR()    __builtin_amdgcn_s_barrier()
#define SCHED0() __builtin_amdgcn_sched_barrier(0)
#define LGKM0()  asm volatile("s_waitcnt lgkmcnt(0)" ::: "memory")

    // prologue: stage all 4 units of tile 0; publish u0-u2 (u3 covered at c0.p0)
    STAGEU(0, 0, 0); STAGEU(0, 0, 1); STAGEU(0, 0, 2); STAGEU(0, 0, 3);
    asm volatile("s_waitcnt vmcnt(2)" ::: "memory");
    BAR();

    bf16x8 bB00, bB01, bB10, bB11, bB20, bB21, bB30, bB31;
    bf16x8 a0_, a1_, a2_, a3_;

    #pragma unroll 1
    for (int c = 0; c < NT - 1; ++c) {
        const int buf = c & 1, nb = buf ^ 1;
        // ---- p0: reads B(all)+A q0-1; stage u0,u1,u2(next); vmcnt(6) covers u3(cur); BAR ----
        SCHED0();
        LDB(bB00, buf, 0, 0); LDB(bB01, buf, 0, 1);
        LDB(bB10, buf, 1, 0); LDB(bB11, buf, 1, 1);
        LDB(bB20, buf, 2, 0); LDB(bB21, buf, 2, 1);
        LDB(bB30, buf, 3, 0); LDB(bB31, buf, 3, 1);
        LDA(a0_, buf, 0, 0); LDA(a1_, buf, 0, 1); LDA(a2_, buf, 1, 0); LDA(a3_, buf, 1, 1);
        STAGEU(nb, c + 1, 0); STAGEU(nb, c + 1, 1); STAGEU(nb, c + 1, 2);
        asm volatile("s_waitcnt vmcnt(6)" ::: "memory");
        BAR(); LGKM0(); SCHED0();
        MFMA16(0);
        // ---- p1 (no barrier): reads A q2-3 (u2, already published) ----
        SCHED0();
        LDA(a0_, buf, 2, 0); LDA(a1_, buf, 2, 1); LDA(a2_, buf, 3, 0); LDA(a3_, buf, 3, 1);
        LGKM0(); SCHED0();
        MFMA16(1);
        // ---- p2: reads A q4-5 (u3); vmcnt(0) drains u0-u2(next), 2 phases old; BAR ----
        SCHED0();
        LDA(a0_, buf, 4, 0); LDA(a1_, buf, 4, 1); LDA(a2_, buf, 5, 0); LDA(a3_, buf, 5, 1);
        asm volatile("s_waitcnt vmcnt(0)" ::: "memory");
        BAR(); LGKM0(); SCHED0();
        MFMA16(2);
        // ---- p3 (no barrier): reads A q6-7; stage u3(next) (region-disjoint WAR) ----
        SCHED0();
        LDA(a0_, buf, 6, 0); LDA(a1_, buf, 6, 1); LDA(a2_, buf, 7, 0); LDA(a3_, buf, 7, 1);
        STAGEU(nb, c + 1, 3);
        LGKM0(); SCHED0();
        MFMA16(3);
    }
    // ---- peeled tail tile 23 ----
    {
        const int buf = (NT - 1) & 1;
        SCHED0();
        LDB(bB00, buf, 0, 0); LDB(bB01, buf, 0, 1);
        LDB(bB10, buf, 1, 0); LDB(bB11, buf, 1, 1);
        LDB(bB20, buf, 2, 0); LDB(bB21, buf, 2, 1);
        LDB(bB30, buf, 3, 0); LDB(bB31, buf, 3, 1);
        LDA(a0_, buf, 0, 0); LDA(a1_, buf, 0, 1); LDA(a2_, buf, 1, 0); LDA(a3_, buf, 1, 1);
        asm volatile("s_waitcnt vmcnt(0)" ::: "memory");   // drain u3(23)
        BAR(); LGKM0(); SCHED0();
        MFMA16(0);
        SCHED0();
        LDA(a0_, buf, 2, 0); LDA(a1_, buf, 2, 1); LDA(a2_, buf, 3, 0); LDA(a3_, buf, 3, 1);
        LGKM0(); SCHED0();
        MFMA16(1);
        SCHED0();
        LDA(a0_, buf, 4, 0); LDA(a1_, buf, 4, 1); LDA(a2_, buf, 5, 0); LDA(a3_, buf, 5, 1);
        LGKM0(); SCHED0();
        MFMA16(2);
        SCHED0();
        LDA(a0_, buf, 6, 0); LDA(a1_, buf, 6, 1); LDA(a2_, buf, 7, 0); LDA(a3_, buf, 7, 1);
        LGKM0(); SCHED0();
        MFMA16(3);
    }
#undef STAGEU
#undef LDA
#undef LDB
#undef MFMA16

    const float sc = scale_p[0];
    #pragma unroll
    for (int m = 0; m < 8; ++m) {
        #pragma unroll
        for (int j = 0; j < 4; ++j) {
            int co = co0 + m * 32 + wr * 16 + lhi * 4 + j;
            float bv = bias[co];
            size_t orow = ((size_t)b * COUT + co) * LEN + l0 + wc * 64;
            #pragma unroll
            for (int n = 0; n < 4; ++n)
                out[orow + n * 16 + llo] = sc * acc[m][n][j] + bv;
        }
    }
}

// ---- fallback (no x prepass) — only if ws too small ----
__global__ __launch_bounds__(256, 2) void conv_fb_kernel(
    const float* __restrict__ x,
    const unsigned short* __restrict__ wb,
    const float* __restrict__ scale_p,
    const float* __restrict__ bias,
    float* __restrict__ out)
{
    __shared__ char xT[132 * 128];
    const int bid = blockIdx.x;
    const int logical = (bid & 7) * 512 + (bid >> 3);
    const int co_tile = logical & 3;
    const int n_tile  = logical >> 2;
    const int b   = n_tile >> 6;
    const int l0  = (n_tile & 63) * 128;
    const int co0 = co_tile * 128;
    const int tid  = threadIdx.x;
    const int lane = tid & 63;
    const int wid  = tid >> 6;
    const int wr = wid >> 1, wc = wid & 1;
    const int lhi = lane >> 4;
    const int llo = lane & 15;
    f32x4 acc[4][4] = {};
    const float* xb = x + (size_t)b * CIN * LEN;

    for (int ci0 = 0; ci0 < CIN; ci0 += 64) {
        __syncthreads();
        for (int it = tid; it < 132 * 8; it += 256) {
            int c = it % 132;
            int o = it / 132;
            int l = l0 - 1 + c;
            float v[8];
            if (l >= 0 && l < LEN) {
                const float* src = xb + (size_t)(ci0 + o * 8) * LEN + l;
                #pragma unroll
                for (int j = 0; j < 8; ++j) v[j] = src[(size_t)j * LEN];
            } else {
                #pragma unroll
                for (int j = 0; j < 8; ++j) v[j] = 0.f;
            }
            union { bf16x8 v8; unsigned short s[8]; } pk;
            #pragma unroll
            for (int j = 0; j < 8; ++j) pk.s[j] = f2bf(v[j]);
            int byte = c * 128 + ((o * 16) ^ ((c & 7) << 4));
            *reinterpret_cast<bf16x8*>(xT + byte) = pk.v8;
        }
        __syncthreads();
        #pragma unroll
        for (int t = 0; t < KW; ++t) {
            #pragma unroll
            for (int s = 0; s < 2; ++s) {
                bf16x8 af[4];
                #pragma unroll
                for (int m = 0; m < 4; ++m)
                    af[m] = *reinterpret_cast<const bf16x8*>(
                        wb + (size_t)(co0 + wr * 64 + m * 16 + llo) * (KW * CIN)
                           + t * CIN + ci0 + s * 32 + 8 * lhi);
                bf16x8 bfr[4];
                #pragma unroll
                for (int n = 0; n < 4; ++n) {
                    int col = wc * 64 + n * 16 + llo + t;
                    int byte = col * 128 + (((s * 32 + 8 * lhi) * 2) ^ ((col & 7) << 4));
                    bfr[n] = *reinterpret_cast<const bf16x8*>(xT + byte);
                }
                #pragma unroll
                for (int m = 0; m < 4; ++m)
                    #pragma unroll
                    for (int n = 0; n < 4; ++n)
                        acc[m][n] = __builtin_amdgcn_mfma_f32_16x16x32_bf16(af[m], bfr[n], acc[m][n], 0, 0, 0);
            }
        }
    }
    const float sc = scale_p[0];
    #pragma unroll
    for (int m = 0; m < 4; ++m) {
        #pragma unroll
        for (int j = 0; j < 4; ++j) {
            int co = co0 + wr * 64 + m * 16 + lhi * 4 + j;
            float bv = bias[co];
            size_t orow = ((size_t)b * COUT + co) * LEN + l0 + wc * 64;
            #pragma unroll
            for (int n = 0; n < 4; ++n)
                out[orow + n * 16 + llo] = sc * acc[m][n][j] + bv;
        }
    }
}

extern "C" void kernel_launch(void* const* d_in, const int* in_sizes, int n_in,
                              void* d_out, int out_size, void* d_ws, size_t ws_size,
                              hipStream_t stream) {
    const float* x    = (const float*)d_in[0];
    const int*   qw   = (const int*)d_in[1];
    const float* sc   = (const float*)d_in[2];
    const float* bias = (const float*)d_in[3];
    float* out = (float*)d_out;
    unsigned short* wb = (unsigned short*)d_ws;

    wconv_kernel<<<(WB_ELEMS + 255) / 256, 256, 0, stream>>>(qw, wb);

    if (ws_size >= WB_BYTES + XS_BYTES) {
        unsigned short* xsw = (unsigned short*)((char*)d_ws + WB_BYTES);
        xprep_kernel<<<NB * 8 * (LEN / 64), 256, 0, stream>>>(x, xsw);
        conv_kernel<<<(COUT / BM2) * (NB * LEN / BN2), 512, 0, stream>>>(xsw, wb, sc, bias, out);
    } else {
        conv_fb_kernel<<<4096, 256, 0, stream>>>(x, wb, sc, bias, out);
    }
}

// Round 14
// 296.428 us; speedup vs baseline: 1.7958x; 1.0323x over previous
//
#include <hip/hip_runtime.h>
#include <hip/hip_bf16.h>

#define CIN   512
#define COUT  512
#define LEN   8192
#define NB    16
#define KW    3
#define PROWS 8200          // padded l-rows per batch (p = l+1)

#define WB_ELEMS (COUT * CIN * KW)
#define WB_BYTES ((size_t)WB_ELEMS * 2)
#define XS_BYTES ((size_t)NB * PROWS * CIN * 2)

#define XPREP_BLOCKS (NB * 8 * (LEN / 64))   // 16384
#define WCONV_BLOCKS ((WB_ELEMS + 255) / 256)

// main kernel: 256x256 tile, BK=64, 8 waves, r8 schedule, 32x32x16 MFMA
#define BM2 256
#define BN2 256
#define BK3 64
#define NT  24               // K-tiles, tap innermost
#define TILE3 (BM2 * BK3 * 2)

typedef __attribute__((ext_vector_type(4)))  float f32x4;
typedef __attribute__((ext_vector_type(16))) float f32x16;
typedef __attribute__((ext_vector_type(8)))  short bf16x8;

static __device__ __forceinline__ unsigned short f2bf(float f) {
    union { float f; unsigned u; } cv; cv.f = f;
    return (unsigned short)((cv.u + 0x7fffu + ((cv.u >> 16) & 1u)) >> 16);
}

// ---- merged prep: blocks [0,16384) transpose x; blocks [16384, +3072) dequant W ----
__global__ __launch_bounds__(256) void prep_kernel(const float* __restrict__ x,
                                                   const int* __restrict__ q,
                                                   unsigned short* __restrict__ xs,
                                                   unsigned short* __restrict__ wb) {
    __shared__ char T[64 * 132];
    int blk = blockIdx.x;
    int tid = threadIdx.x;

    if (blk >= XPREP_BLOCKS) {
        // wconv role: qweight[co][ci][t] -> wb[co][t*512+ci] (bf16)
        int idx = (blk - XPREP_BLOCKS) * 256 + tid;
        if (idx < WB_ELEMS) {
            int co = idx / (KW * CIN);
            int r  = idx - co * (KW * CIN);
            int t  = r >> 9;
            int ci = r & 511;
            wb[idx] = f2bf((float)q[(co * CIN + ci) * KW + t]);
        }
        return;
    }

    // xprep role: fp32 [b][ci][l] -> bf16 [b][1+l][ci]; zero halo rows
    int b   = blk >> 10;
    int ci0 = ((blk >> 7) & 7) * 64;
    int l0  = (blk & 127) * 64;

    if (l0 == 0 && tid < 64)
        xs[((size_t)b * PROWS + 0) * CIN + ci0 + tid] = 0;
    if (l0 == (LEN - 64) && tid < 64)
        xs[((size_t)b * PROWS + (LEN + 1)) * CIN + ci0 + tid] = 0;

    const float* src = x + ((size_t)b * CIN + ci0) * LEN + l0;
    for (int i = tid; i < 64 * 16; i += 256) {
        int r = i >> 4, c4 = i & 15;
        f32x4 v = *(const f32x4*)(src + (size_t)r * LEN + c4 * 4);
        unsigned lo = (unsigned)f2bf(v[0]) | ((unsigned)f2bf(v[1]) << 16);
        unsigned hi = (unsigned)f2bf(v[2]) | ((unsigned)f2bf(v[3]) << 16);
        char* p = T + r * 132 + c4 * 8;
        *(unsigned*)p       = lo;
        *(unsigned*)(p + 4) = hi;
    }
    __syncthreads();
    unsigned short* dst = xs + ((size_t)b * PROWS + 1 + l0) * CIN + ci0;
    for (int i = tid; i < 64 * 8; i += 256) {
        int l = i >> 3, c8 = i & 7;
        union { bf16x8 v; unsigned short s[8]; } pk;
        #pragma unroll
        for (int j = 0; j < 8; ++j)
            pk.s[j] = *(const unsigned short*)(T + (c8 * 8 + j) * 132 + l * 2);
        *(bf16x8*)(dst + (size_t)l * CIN + c8 * 8) = pk.v;
    }
}

// ---- main conv: r8 schedule (4 phases, 1 barrier each, counted vmcnt), 32x32x16 MFMA ----
__global__ __launch_bounds__(512, 2) void conv_kernel(
    const unsigned short* __restrict__ xs,
    const unsigned short* __restrict__ wb,
    const float* __restrict__ scale_p,
    const float* __restrict__ bias,
    float* __restrict__ out)
{
    __shared__ char sA[2][TILE3];    // 2 x 32 KB
    __shared__ char sB[2][TILE3];    // 2 x 32 KB

    const int bid = blockIdx.x;
    const int logical = (bid & 7) * 128 + (bid >> 3);   // XCD swizzle, 1024 = 8*128
    const int co_tile = logical & 1;
    const int l_tile  = logical >> 1;
    const int b   = l_tile >> 5;
    const int l0  = (l_tile & 31) * BN2;
    const int co0 = co_tile * BM2;

    const int tid  = threadIdx.x;
    const int lane = tid & 63;
    const int wid  = tid >> 6;
    const int wr   = wid >> 2;        // 0..1
    const int wc   = wid & 3;         // 0..3
    const int la   = lane & 31;
    const int lh   = lane >> 5;

    f32x16 acc[4][2] = {};            // [mb][nb]; A row base = mb*64 + wr*32

    const char* xsB = (const char*)(xs + ((size_t)b * PROWS + l0) * CIN);
    const char* wbB = (const char*)wb + (size_t)co0 * (KW * CIN * 2);

    // stage unit u of K-tile c into buf: u0=B rows0-127, u1=B rows128-255, u2=A h0, u3=A h1
#define STAGEU(buf_, c_, u_) do {                                                            \
    int tap_ = (c_) % KW;  int ci0_ = ((c_) / KW) * BK3;                                     \
    int rowoff_ = ((u_) & 1) * 128;                                                          \
    const char* src0_; size_t rstride_; char* dst0_;                                         \
    if ((u_) < 2) { src0_ = xsB + ((size_t)(tap_ + rowoff_) * CIN + ci0_) * 2;               \
                    rstride_ = CIN * 2; dst0_ = &sB[buf_][rowoff_ * 128]; }                   \
    else          { src0_ = wbB + (size_t)rowoff_ * (KW * CIN * 2)                           \
                            + ((size_t)tap_ * CIN + ci0_) * 2;                               \
                    rstride_ = KW * CIN * 2; dst0_ = &sA[buf_][rowoff_ * 128]; }             \
    _Pragma("unroll")                                                                        \
    for (int kk_ = 0; kk_ < 2; ++kk_) {                                                      \
        int it_ = tid + kk_ * 512;                                                           \
        int r_ = it_ >> 3, q_ = it_ & 7;                                                     \
        __builtin_amdgcn_global_load_lds(                                                    \
            (const __attribute__((address_space(1))) unsigned int*)                          \
                (src0_ + (size_t)r_ * rstride_ + ((q_ * 16) ^ ((r_ & 7) << 4))),             \
            (__attribute__((address_space(3))) unsigned int*)(dst0_ + it_ * 16),             \
            16, 0, 0);                                                                       \
    } } while (0)

    // fragment reads (32x32x16): lane holds 8 K-contiguous bf16 at k = s*16 + 8*lh
#define LDA(d_, buf_, mb_, s_) do { int row_ = (mb_) * 64 + wr * 32 + la;                    \
    d_ = *(const bf16x8*)(&sA[buf_][0] + row_ * 128                                          \
                          + (((s_) * 32 + lh * 16) ^ ((row_ & 7) << 4))); } while (0)
#define LDB(d_, buf_, nb_, s_) do { int row_ = wc * 64 + (nb_) * 32 + la;                    \
    d_ = *(const bf16x8*)(&sB[buf_][0] + row_ * 128                                          \
                          + (((s_) * 32 + lh * 16) ^ ((row_ & 7) << 4))); } while (0)

    // 8 MFMA32 per phase: m-pair (MB_,MB_+1) x n0/n1 x s-pair; a0=A(MB,S0) a1=A(MB,S1)
    // a2=A(MB+1,S0) a3=A(MB+1,S1); B args are (n0,S0),(n1,S0),(n0,S1),(n1,S1)
#define MFMA8(MB_, B00_, B01_, B10_, B11_) do {                                              \
    __builtin_amdgcn_s_setprio(1);                                                           \
    acc[(MB_)  ][0] = __builtin_amdgcn_mfma_f32_32x32x16_bf16(a0_, B00_, acc[(MB_)  ][0],0,0,0); \
    acc[(MB_)  ][1] = __builtin_amdgcn_mfma_f32_32x32x16_bf16(a0_, B01_, acc[(MB_)  ][1],0,0,0); \
    acc[(MB_)+1][0] = __builtin_amdgcn_mfma_f32_32x32x16_bf16(a2_, B00_, acc[(MB_)+1][0],0,0,0); \
    acc[(MB_)+1][1] = __builtin_amdgcn_mfma_f32_32x32x16_bf16(a2_, B01_, acc[(MB_)+1][1],0,0,0); \
    acc[(MB_)  ][0] = __builtin_amdgcn_mfma_f32_32x32x16_bf16(a1_, B10_, acc[(MB_)  ][0],0,0,0); \
    acc[(MB_)  ][1] = __builtin_amdgcn_mfma_f32_32x32x16_bf16(a1_, B11_, acc[(MB_)  ][1],0,0,0); \
    acc[(MB_)+1][0] = __builtin_amdgcn_mfma_f32_32x32x16_bf16(a3_, B10_, acc[(MB_)+1][0],0,0,0); \
    acc[(MB_)+1][1] = __builtin_amdgcn_mfma_f32_32x32x16_bf16(a3_, B11_, acc[(MB_)+1][1],0,0,0); \
    __builtin_amdgcn_s_setprio(0);                                                           \
    } while (0)

#define BAR()    __builtin_amdgcn_s_barrier()
#define SCHED0() __builtin_amdgcn_sched_barrier(0)
#define LGKM0()  asm volatile("s_waitcnt lgkmcnt(0)" ::: "memory")

    // prologue: stage all 4 units of tile 0; first 3 must land before p0 reads
    STAGEU(0, 0, 0); STAGEU(0, 0, 1); STAGEU(0, 0, 2); STAGEU(0, 0, 3);
    asm volatile("s_waitcnt vmcnt(2)" ::: "memory");
    BAR();

    bf16x8 b00, b01, b10, b11, b20, b21, b30, b31;   // B[s][n], live across the tile
    bf16x8 a0_, a1_, a2_, a3_;

    #pragma unroll 1
    for (int c = 0; c < NT - 1; ++c) {
        const int buf = c & 1, nb = buf ^ 1;
        // ---- p0: all B + A(mb0-1, s0-1); stage u0(next) ----
        SCHED0();
        LDB(b00, buf, 0, 0); LDB(b01, buf, 1, 0);
        LDB(b10, buf, 0, 1); LDB(b11, buf, 1, 1);
        LDB(b20, buf, 0, 2); LDB(b21, buf, 1, 2);
        LDB(b30, buf, 0, 3); LDB(b31, buf, 1, 3);
        LDA(a0_, buf, 0, 0); LDA(a1_, buf, 0, 1); LDA(a2_, buf, 1, 0); LDA(a3_, buf, 1, 1);
        STAGEU(nb, c + 1, 0);
        BAR(); LGKM0(); SCHED0();
        MFMA8(0, b00, b01, b10, b11);
        // ---- p1: A(mb0-1, s2-3); stage u1(next); wait for Ah1(cur) ----
        SCHED0();
        LDA(a0_, buf, 0, 2); LDA(a1_, buf, 0, 3); LDA(a2_, buf, 1, 2); LDA(a3_, buf, 1, 3);
        STAGEU(nb, c + 1, 1);
        asm volatile("s_waitcnt vmcnt(4)" ::: "memory");
        BAR(); LGKM0(); SCHED0();
        MFMA8(0, b20, b21, b30, b31);
        // ---- p2: A(mb2-3, s0-1); stage u2(next) ----
        SCHED0();
        LDA(a0_, buf, 2, 0); LDA(a1_, buf, 2, 1); LDA(a2_, buf, 3, 0); LDA(a3_, buf, 3, 1);
        STAGEU(nb, c + 1, 2);
        BAR(); LGKM0(); SCHED0();
        MFMA8(2, b00, b01, b10, b11);
        // ---- p3: A(mb2-3, s2-3); stage u3(next); wait for u0-u2(next) ----
        SCHED0();
        LDA(a0_, buf, 2, 2); LDA(a1_, buf, 2, 3); LDA(a2_, buf, 3, 2); LDA(a3_, buf, 3, 3);
        STAGEU(nb, c + 1, 3);
        asm volatile("s_waitcnt vmcnt(2)" ::: "memory");
        BAR(); LGKM0(); SCHED0();
        MFMA8(2, b20, b21, b30, b31);
    }
    // ---- peeled tail tile 23 (no stages); drain u3 with vmcnt(0) before mb2-3 reads ----
    {
        const int buf = (NT - 1) & 1;
        SCHED0();
        LDB(b00, buf, 0, 0); LDB(b01, buf, 1, 0);
        LDB(b10, buf, 0, 1); LDB(b11, buf, 1, 1);
        LDB(b20, buf, 0, 2); LDB(b21, buf, 1, 2);
        LDB(b30, buf, 0, 3); LDB(b31, buf, 1, 3);
        LDA(a0_, buf, 0, 0); LDA(a1_, buf, 0, 1); LDA(a2_, buf, 1, 0); LDA(a3_, buf, 1, 1);
        BAR(); LGKM0(); SCHED0();
        MFMA8(0, b00, b01, b10, b11);
        SCHED0();
        LDA(a0_, buf, 0, 2); LDA(a1_, buf, 0, 3); LDA(a2_, buf, 1, 2); LDA(a3_, buf, 1, 3);
        asm volatile("s_waitcnt vmcnt(0)" ::: "memory");
        BAR(); LGKM0(); SCHED0();
        MFMA8(0, b20, b21, b30, b31);
        SCHED0();
        LDA(a0_, buf, 2, 0); LDA(a1_, buf, 2, 1); LDA(a2_, buf, 3, 0); LDA(a3_, buf, 3, 1);
        BAR(); LGKM0(); SCHED0();
        MFMA8(2, b00, b01, b10, b11);
        SCHED0();
        LDA(a0_, buf, 2, 2); LDA(a1_, buf, 2, 3); LDA(a2_, buf, 3, 2); LDA(a3_, buf, 3, 3);
        LGKM0(); SCHED0();
        MFMA8(2, b20, b21, b30, b31);
    }
#undef STAGEU
#undef LDA
#undef LDB
#undef MFMA8

    // epilogue: D layout (32x32): col = lane&31, row = (rg&3) + 8*(rg>>2) + 4*(lane>>5)
    const float sc = scale_p[0];
    #pragma unroll
    for (int mb = 0; mb < 4; ++mb) {
        const int coB = co0 + mb * 64 + wr * 32 + 4 * lh;
        #pragma unroll
        for (int rg = 0; rg < 16; ++rg) {
            int co = coB + (rg & 3) + 8 * (rg >> 2);
            float bv = bias[co];
            size_t orow = ((size_t)b * COUT + co) * LEN + l0 + wc * 64 + la;
            out[orow]      = sc * acc[mb][0][rg] + bv;
            out[orow + 32] = sc * acc[mb][1][rg] + bv;
        }
    }
}

// ---- standalone wconv (fallback path only) ----
__global__ __launch_bounds__(256) void wconv_kernel(const int* __restrict__ q,
                                                    unsigned short* __restrict__ wb) {
    int idx = blockIdx.x * 256 + threadIdx.x;
    if (idx >= WB_ELEMS) return;
    int co = idx / (KW * CIN);
    int r  = idx - co * (KW * CIN);
    int t  = r >> 9;
    int ci = r & 511;
    wb[idx] = f2bf((float)q[(co * CIN + ci) * KW + t]);
}

// ---- fallback (no x prepass) — only if ws too small ----
__global__ __launch_bounds__(256, 2) void conv_fb_kernel(
    const float* __restrict__ x,
    const unsigned short* __restrict__ wb,
    const float* __restrict__ scale_p,
    const float* __restrict__ bias,
    float* __restrict__ out)
{
    __shared__ char xT[132 * 128];
    const int bid = blockIdx.x;
    const int logical = (bid & 7) * 512 + (bid >> 3);
    const int co_tile = logical & 3;
    const int n_tile  = logical >> 2;
    const int b   = n_tile >> 6;
    const int l0  = (n_tile & 63) * 128;
    const int co0 = co_tile * 128;
    const int tid  = threadIdx.x;
    const int lane = tid & 63;
    const int wid  = tid >> 6;
    const int wr = wid >> 1, wc = wid & 1;
    const int lhi = lane >> 4;
    const int llo = lane & 15;
    f32x4 acc[4][4] = {};
    const float* xb = x + (size_t)b * CIN * LEN;

    for (int ci0 = 0; ci0 < CIN; ci0 += 64) {
        __syncthreads();
        for (int it = tid; it < 132 * 8; it += 256) {
            int c = it % 132;
            int o = it / 132;
            int l = l0 - 1 + c;
            float v[8];
            if (l >= 0 && l < LEN) {
                const float* src = xb + (size_t)(ci0 + o * 8) * LEN + l;
                #pragma unroll
                for (int j = 0; j < 8; ++j) v[j] = src[(size_t)j * LEN];
            } else {
                #pragma unroll
                for (int j = 0; j < 8; ++j) v[j] = 0.f;
            }
            union { bf16x8 v8; unsigned short s[8]; } pk;
            #pragma unroll
            for (int j = 0; j < 8; ++j) pk.s[j] = f2bf(v[j]);
            int byte = c * 128 + ((o * 16) ^ ((c & 7) << 4));
            *reinterpret_cast<bf16x8*>(xT + byte) = pk.v8;
        }
        __syncthreads();
        #pragma unroll
        for (int t = 0; t < KW; ++t) {
            #pragma unroll
            for (int s = 0; s < 2; ++s) {
                bf16x8 af[4];
                #pragma unroll
                for (int m = 0; m < 4; ++m)
                    af[m] = *reinterpret_cast<const bf16x8*>(
                        wb + (size_t)(co0 + wr * 64 + m * 16 + llo) * (KW * CIN)
                           + t * CIN + ci0 + s * 32 + 8 * lhi);
                bf16x8 bfr[4];
                #pragma unroll
                for (int n = 0; n < 4; ++n) {
                    int col = wc * 64 + n * 16 + llo + t;
                    int byte = col * 128 + (((s * 32 + 8 * lhi) * 2) ^ ((col & 7) << 4));
                    bfr[n] = *reinterpret_cast<const bf16x8*>(xT + byte);
                }
                #pragma unroll
                for (int m = 0; m < 4; ++m)
                    #pragma unroll
                    for (int n = 0; n < 4; ++n)
                        acc[m][n] = __builtin_amdgcn_mfma_f32_16x16x32_bf16(af[m], bfr[n], acc[m][n], 0, 0, 0);
            }
        }
    }
    const float sc = scale_p[0];
    #pragma unroll
    for (int m = 0; m < 4; ++m) {
        #pragma unroll
        for (int j = 0; j < 4; ++j) {
            int co = co0 + wr * 64 + m * 16 + lhi * 4 + j;
            float bv = bias[co];
            size_t orow = ((size_t)b * COUT + co) * LEN + l0 + wc * 64;
            #pragma unroll
            for (int n = 0; n < 4; ++n)
                out[orow + n * 16 + llo] = sc * acc[m][n][j] + bv;
        }
    }
}

extern "C" void kernel_launch(void* const* d_in, const int* in_sizes, int n_in,
                              void* d_out, int out_size, void* d_ws, size_t ws_size,
                              hipStream_t stream) {
    const float* x    = (const float*)d_in[0];
    const int*   qw   = (const int*)d_in[1];
    const float* sc   = (const float*)d_in[2];
    const float* bias = (const float*)d_in[3];
    float* out = (float*)d_out;
    unsigned short* wb = (unsigned short*)d_ws;

    if (ws_size >= WB_BYTES + XS_BYTES) {
        unsigned short* xsw = (unsigned short*)((char*)d_ws + WB_BYTES);
        prep_kernel<<<XPREP_BLOCKS + WCONV_BLOCKS, 256, 0, stream>>>(x, qw, xsw, wb);
        conv_kernel<<<(COUT / BM2) * (NB * LEN / BN2), 512, 0, stream>>>(xsw, wb, sc, bias, out);
    } else {
        wconv_kernel<<<WCONV_BLOCKS, 256, 0, stream>>>(qw, wb);
        conv_fb_kernel<<<4096, 256, 0, stream>>>(x, wb, sc, bias, out);
    }
}